// Round 9
// baseline (123.480 us; speedup 1.0000x reference)
//
#include <hip/hip_runtime.h>
#include <math.h>

#define B_ 2
#define T_ 128
#define Cc 384
#define NH_ 6
#define HD 64
#define Hh 768
#define P_ 4
#define M_ 16
#define PL_ 20
#define TT 148

typedef unsigned short u16;
typedef short short8 __attribute__((ext_vector_type(8)));
typedef float f32x4 __attribute__((ext_vector_type(4)));

// ---------- helpers ----------
__device__ __forceinline__ u16 f2bf(float f) {
  unsigned int u = __float_as_uint(f);
  u += 0x7FFFu + ((u >> 16) & 1u);
  return (u16)(u >> 16);
}
__device__ __forceinline__ float siluf(float v) { return v / (1.f + expf(-v)); }
__device__ __forceinline__ float geluf(float v) {
  float x3 = v*v*v;
  return 0.5f*v*(1.f + tanhf(0.7978845608028654f*(v + 0.044715f*x3)));
}
template<int ACT> __device__ __forceinline__ float act_apply(float v) {
  if (ACT == 1) return geluf(v);
  if (ACT == 2) return siluf(v);
  return v;
}
__device__ __forceinline__ float coef_f(int k) {
  float e = (float)(T_ - k);
  return (exp2f(e * -0.00144342f) - exp2f(e * -0.15200310f)) * (1.0f/0.099f);
}
__device__ __forceinline__ void st_tr4(u16* dst, float v0, float v1, float v2, float v3) {
  union { u16 u[4]; uint2 d; } q;
  q.u[0]=f2bf(v0); q.u[1]=f2bf(v1); q.u[2]=f2bf(v2); q.u[3]=f2bf(v3);
  *(uint2*)dst = q.d;
}
__device__ __forceinline__ float wave_sum(float s) {
  #pragma unroll
  for (int off = 32; off; off >>= 1) s += __shfl_xor(s, off);
  return s;
}

// ---------- params ----------
struct Prm {
  const float *x,*c_attn_w,*c_attn_b,*c_proj_w,*c_proj_b,*ln1_g,*ln1_b,*ln2_g,*ln2_b,
              *fc_w,*fc_b,*pr_w,*pr_b,*mem_w1,*mem_w2,*wk,*wv,*mem_q,*persist;
  float *qkv,*vmb,*h1,*h2,*hhb,*outp;
  u16 *cattnT,*cprojT,*wkT,*wvT,*fcT,*prT,*w1tr,*w2tr,*w2pl,*memq,*seqb,*yb,*h2n,
      *fco,*h2b,*kmb,*kmTc,*ab,*abTc,*errB,*errT,*dhT,*w1fT,*w2fT,*ub;
  float scale, dpow;
};

// ---------- MFMA split-K core: 4 waves share a 32x64 tile over K/4 each ----------
template<int KSTEPS>   // per-wave K-steps; total K = KSTEPS*128
__device__ __forceinline__ void mfma_core(const u16* __restrict__ A,
    const u16* __restrict__ BT, int M, int mBase, int nBase, float (*red)[64][36])
{
  const long K = (long)KSTEPS * 128;
  int l = threadIdx.x & 63, w = threadIdx.x >> 6;
  int lr = l & 15, kg = l >> 4;
  long r0 = (long)min(mBase + lr, M - 1);
  long r1 = (long)min(mBase + 16 + lr, M - 1);
  long c0 = nBase + lr;
  long ko = (long)w * KSTEPS * 32 + kg * 8;
  const u16* pa0 = A + r0*K + ko;
  const u16* pa1 = A + r1*K + ko;
  const u16* pb0 = BT + c0*K + ko;
  const u16* pb1 = BT + (c0+16)*K + ko;
  const u16* pb2 = BT + (c0+32)*K + ko;
  const u16* pb3 = BT + (c0+48)*K + ko;
  f32x4 acc[2][4] = {};
  short8 a0 = *(const short8*)pa0, a1 = *(const short8*)pa1;
  short8 b0 = *(const short8*)pb0, b1 = *(const short8*)pb1;
  short8 b2 = *(const short8*)pb2, b3 = *(const short8*)pb3;
  #pragma unroll
  for (int t = 0; t < KSTEPS; ++t) {
    short8 xa0=a0, xa1=a1, xb0=b0, xb1=b1, xb2=b2, xb3=b3;
    if (t+1 < KSTEPS) {
      int o = (t+1)*32;
      a0 = *(const short8*)(pa0+o); a1 = *(const short8*)(pa1+o);
      b0 = *(const short8*)(pb0+o); b1 = *(const short8*)(pb1+o);
      b2 = *(const short8*)(pb2+o); b3 = *(const short8*)(pb3+o);
    }
    acc[0][0] = __builtin_amdgcn_mfma_f32_16x16x32_bf16(xa0, xb0, acc[0][0], 0,0,0);
    acc[0][1] = __builtin_amdgcn_mfma_f32_16x16x32_bf16(xa0, xb1, acc[0][1], 0,0,0);
    acc[0][2] = __builtin_amdgcn_mfma_f32_16x16x32_bf16(xa0, xb2, acc[0][2], 0,0,0);
    acc[0][3] = __builtin_amdgcn_mfma_f32_16x16x32_bf16(xa0, xb3, acc[0][3], 0,0,0);
    acc[1][0] = __builtin_amdgcn_mfma_f32_16x16x32_bf16(xa1, xb0, acc[1][0], 0,0,0);
    acc[1][1] = __builtin_amdgcn_mfma_f32_16x16x32_bf16(xa1, xb1, acc[1][1], 0,0,0);
    acc[1][2] = __builtin_amdgcn_mfma_f32_16x16x32_bf16(xa1, xb2, acc[1][2], 0,0,0);
    acc[1][3] = __builtin_amdgcn_mfma_f32_16x16x32_bf16(xa1, xb3, acc[1][3], 0,0,0);
  }
  #pragma unroll
  for (int i = 0; i < 2; ++i)
    #pragma unroll
    for (int j = 0; j < 4; ++j)
      *(f32x4*)&red[w][j*16 + lr][i*16 + kg*4] = acc[i][j];
  __syncthreads();
}

__device__ __forceinline__ void reduce8(float (*red)[64][36], float v[8], int& row0, int& col) {
  int tid = threadIdx.x;
  col = tid & 63;
  row0 = (tid >> 6) * 8;
  #pragma unroll
  for (int q = 0; q < 2; ++q) {
    f32x4 s = *(f32x4*)&red[0][col][row0 + q*4];
    s += *(f32x4*)&red[1][col][row0 + q*4];
    s += *(f32x4*)&red[2][col][row0 + q*4];
    s += *(f32x4*)&red[3][col][row0 + q*4];
    v[q*4+0] = s[0]; v[q*4+1] = s[1]; v[q*4+2] = s[2]; v[q*4+3] = s[3];
  }
}

template<int KSTEPS, int ACT, bool BIAS, bool RES, bool STF, bool STB, bool STTR>
__device__ __forceinline__ void gemm_task(const u16* A, const u16* BT,
    const float* bias, const float* res, float rscale,
    float* outF, u16* outB, u16* outT, int M, int N,
    int xx, int yy, float (*red)[64][36])
{
  int mBase = yy*32, nBase = xx*64;
  mfma_core<KSTEPS>(A, BT, M, mBase, nBase, red);
  float v[8]; int row0, col;
  reduce8(red, v, row0, col);
  int c = nBase + col;
  float bv = BIAS ? bias[c] : 0.f;
  #pragma unroll
  for (int q = 0; q < 8; ++q) {
    int r = mBase + row0 + q;
    float val = act_apply<ACT>(v[q] + bv);
    if (RES && r < M) val += rscale * res[(long)r*N + c];
    v[q] = val;
    if (r < M) {
      if (STF) outF[(long)r*N + c] = val;
      if (STB) outB[(long)r*N + c] = f2bf(val);
    }
  }
  if (STTR) {
    #pragma unroll
    for (int q = 0; q < 2; ++q) {
      int r = mBase + row0 + q*4;
      if (r < M) {
        int zz = r >> 7, t0 = r & 127;
        st_tr4(&outT[((long)zz*N + c)*128 + t0], v[q*4], v[q*4+1], v[q*4+2], v[q*4+3]);
      }
    }
  }
}

// ================= K0: transposes + plain converts + LN1 (grid 2952) =================
__global__ __launch_bounds__(256)
void k0_prep(Prm p)
{
  __shared__ float lds[1056];
  const int t = blockIdx.x;
  const int tid = threadIdx.x, w = tid >> 6, lane = tid & 63;
  if (t < 2592) {
    const float* src; u16* dst; int K, N, tile;
    int b = t;
    if (b < 432)       { src=p.c_attn_w; dst=p.cattnT; K=384;  N=1152; tile=b; }
    else if (b < 576)  { src=p.c_proj_w; dst=p.cprojT; K=384;  N=384;  tile=b-432; }
    else if (b < 720)  { src=p.wk;       dst=p.wkT;    K=384;  N=384;  tile=b-576; }
    else if (b < 864)  { src=p.wv;       dst=p.wvT;    K=384;  N=384;  tile=b-720; }
    else if (b < 1440) { src=p.fc_w;     dst=p.fcT;    K=384;  N=1536; tile=b-864; }
    else if (b < 2016) { src=p.pr_w;     dst=p.prT;    K=1536; N=384;  tile=b-1440; }
    else if (b < 2304) { src=p.mem_w1;   dst=p.w1tr;   K=384;  N=768;  tile=b-2016; }
    else               { src=p.mem_w2;   dst=p.w2tr;   K=768;  N=384;  tile=b-2304; }
    int ntx = N >> 5;
    int n0 = (tile % ntx) << 5, k0 = (tile / ntx) << 5;
    float (*fl)[33] = reinterpret_cast<float(*)[33]>(lds);
    int tr = tid >> 3, tc4 = (tid & 7) << 2;
    float4 vv = *(const float4*)&src[(long)(k0 + tr)*N + n0 + tc4];
    fl[tr][tc4] = vv.x; fl[tr][tc4+1] = vv.y; fl[tr][tc4+2] = vv.z; fl[tr][tc4+3] = vv.w;
    __syncthreads();
    st_tr4(&dst[(long)(n0 + tr)*K + k0 + tc4],
           fl[tc4][tr], fl[tc4+1][tr], fl[tc4+2][tr], fl[tc4+3][tr]);
  } else if (t < 2888) {
    int i = (t - 2592)*256 + tid;
    if (i < 73728) {
      float4 v = *(const float4*)&p.mem_w2[(long)i*4];
      st_tr4(&p.w2pl[(long)i*4], v.x, v.y, v.z, v.w);
    } else if (i < 73728 + 1536) {
      int j = i - 73728;
      float4 v = *(const float4*)&p.mem_q[(long)j*4];
      st_tr4(&p.memq[(long)j*4], v.x, v.y, v.z, v.w);
    } else if (i < 73728 + 1536 + 384) {
      int j = i - 73728 - 1536;
      float4 v = *(const float4*)&p.persist[(long)j*4];
      st_tr4(&p.seqb[(long)j*4], v.x, v.y, v.z, v.w);
      st_tr4(&p.seqb[(long)TT*384 + j*4], v.x, v.y, v.z, v.w);
    }
  } else {
    int row = (t - 2888)*4 + w;
    const float* src = p.x + (long)row*384;
    float v[6];
    #pragma unroll
    for (int i = 0; i < 6; ++i) v[i] = src[lane + i*64];
    float mu = wave_sum(v[0]+v[1]+v[2]+v[3]+v[4]+v[5]) * (1.f/384.f);
    float sq = 0.f;
    #pragma unroll
    for (int i = 0; i < 6; ++i) { float d = v[i]-mu; sq += d*d; }
    float rstd = rsqrtf(wave_sum(sq)*(1.f/384.f) + 1e-5f);
    u16* dst = p.seqb + ((long)(row >> 7)*TT + PL_ + (row & 127))*384;
    #pragma unroll
    for (int i = 0; i < 6; ++i) {
      int cc = lane + i*64;
      dst[cc] = f2bf((v[i]-mu)*rstd*p.ln1_g[cc] + p.ln1_b[cc]);
    }
  }
}

// ================= K0c: hid (redundant per block, LDS) + retr slice (grid 6) =================
__global__ __launch_bounds__(256, 1)
void k0c_retr(Prm p)
{
  __shared__ float red[4][64][36];
  __shared__ u16 hidl[16*768];
  // hid = silu(memq @ w1tr), all 12 column-tiles, into LDS
  for (int xx = 0; xx < 12; ++xx) {
    mfma_core<3>(p.memq, p.w1tr, 16, 0, xx*64, red);
    float v[8]; int row0, col;
    reduce8(red, v, row0, col);
    int c = xx*64 + col;
    #pragma unroll
    for (int q = 0; q < 8; ++q) {
      int r = row0 + q;
      if (r < 16) hidl[r*768 + c] = f2bf(siluf(v[q]));
    }
    __syncthreads();
  }
  // retr slice = hid @ w2tr -> seq rows 4..19 (both batches)
  int nBase = blockIdx.x*64;
  mfma_core<6>((const u16*)hidl, p.w2tr, 16, 0, nBase, red);
  float v[8]; int row0, col;
  reduce8(red, v, row0, col);
  int c = nBase + col;
  #pragma unroll
  for (int q = 0; q < 8; ++q) {
    int r = row0 + q;
    if (r < 16) {
      u16 bv = f2bf(v[q]);
      p.seqb[(long)(P_ + r)*384 + c] = bv;
      p.seqb[(long)(TT + P_ + r)*384 + c] = bv;
    }
  }
}

// ================= K1: fused qkv / km / vm (grid 300) =================
__global__ __launch_bounds__(256, 2)
void k1_qkv(Prm p)
{
  __shared__ float red[4][64][36];
  int t = blockIdx.x;
  int xx = t % 30, yy = t / 30;
  int nb = xx * 64;
  const u16* BT; int n0, seg;
  if (nb < 1152)      { BT = p.cattnT; n0 = nb;        seg = 0; }
  else if (nb < 1536) { BT = p.wkT;    n0 = nb - 1152; seg = 1; }
  else                { BT = p.wvT;    n0 = nb - 1536; seg = 2; }
  int mBase = yy*32;
  mfma_core<3>(p.seqb, BT, 296, mBase, n0, red);
  float v[8]; int row0, col;
  reduce8(red, v, row0, col);
  int c = n0 + col;
  if (seg == 0) {
    float bv = p.c_attn_b[c];
    #pragma unroll
    for (int q = 0; q < 8; ++q) {
      int r = mBase + row0 + q;
      if (r < 296) p.qkv[(long)r*1152 + c] = v[q] + bv;
    }
  } else if (seg == 1) {
    #pragma unroll
    for (int q = 0; q < 8; ++q) {
      int r = mBase + row0 + q;
      if (r < 296) {
        int z = r/148, tt2 = r - 20 - z*148;
        if (tt2 >= 0) p.kmb[((long)z*128 + tt2)*384 + c] = f2bf(v[q]);
      }
    }
    #pragma unroll
    for (int q = 0; q < 2; ++q) {
      int r = mBase + row0 + q*4;
      if (r < 296) {
        int z = r/148, t0 = r - 20 - z*148;
        if (t0 >= 0)
          st_tr4(&p.kmTc[((long)z*384 + c)*128 + t0],
                 v[q*4]*coef_f(t0), v[q*4+1]*coef_f(t0+1),
                 v[q*4+2]*coef_f(t0+2), v[q*4+3]*coef_f(t0+3));
      }
    }
  } else {
    #pragma unroll
    for (int q = 0; q < 8; ++q) {
      int r = mBase + row0 + q;
      if (r < 296) {
        int z = r/148, tt2 = r - 20 - z*148;
        if (tt2 >= 0) p.vmb[((long)z*128 + tt2)*384 + c] = v[q];
      }
    }
  }
}

// ================= K2: attention (384) + hh/ab/abTc (96) -> grid 480 =================
__global__ __launch_bounds__(256, 2)
void k2_attn_hh(Prm p)
{
  __shared__ float red[4][64][36];
  const int t = blockIdx.x;
  const int tid = threadIdx.x, w = tid >> 6, lane = tid & 63;
  if (t < 384) {
    float* ldsf = (float*)red;
    float* qs = ldsf + w*64;
    float* pp = ldsf + 256 + w*152;
    int tt = t*4 + w;
    int qr = PL_ + (tt & 127);
    int h  = (tt >> 7) % 6;
    int b  = (tt / 768) & 1;
    const float* base = p.qkv + (long)b*TT*1152;
    qs[lane] = base[(long)qr*1152 + h*64 + lane];
    float mloc = -1e30f;
    for (int k = lane; k < TT; k += 64) {
      float s = -1e30f;
      if (k <= qr) {
        const float* kp = base + (long)k*1152 + 384 + h*64;
        float acc = 0.f;
        #pragma unroll
        for (int d = 0; d < 64; ++d) acc += qs[d]*kp[d];
        s = acc * 0.125f;
      }
      pp[k] = s;
      mloc = fmaxf(mloc, s);
    }
    #pragma unroll
    for (int off = 32; off; off >>= 1) mloc = fmaxf(mloc, __shfl_xor(mloc, off));
    float ssum = 0.f;
    for (int k = lane; k < TT; k += 64) {
      float e = (k <= qr) ? expf(pp[k] - mloc) : 0.f;
      pp[k] = e; ssum += e;
    }
    ssum = wave_sum(ssum);
    float inv = 1.f / ssum;
    float acc = 0.f;
    const float* vb = base + 768 + h*64 + lane;
    int k = 0;
    for (; k + 4 <= qr + 1; k += 4)
      acc += pp[k]*vb[(long)k*1152] + pp[k+1]*vb[(long)(k+1)*1152]
           + pp[k+2]*vb[(long)(k+2)*1152] + pp[k+3]*vb[(long)(k+3)*1152];
    for (; k <= qr; ++k) acc += pp[k]*vb[(long)k*1152];
    p.yb[((long)b*128 + (tt & 127))*384 + h*64 + lane] = f2bf(acc * inv);
  } else {
    int tt2 = t - 384;
    int xx = tt2 % 12, yy = tt2 / 12;
    int mBase = yy*32, nBase = xx*64;
    mfma_core<3>(p.kmb, p.w1tr, 256, mBase, nBase, red);
    float v[8]; int row0, col;
    reduce8(red, v, row0, col);
    int c = nBase + col;
    float s8[8];
    #pragma unroll
    for (int q = 0; q < 8; ++q) {
      int r = mBase + row0 + q;
      p.hhb[(long)r*768 + c] = v[q];
      s8[q] = siluf(v[q]);
      p.ab[(long)r*768 + c] = f2bf(s8[q]);
    }
    #pragma unroll
    for (int q = 0; q < 2; ++q) {
      int r = mBase + row0 + q*4;
      int zz = r >> 7, t0 = r & 127;
      st_tr4(&p.abTc[((long)zz*768 + c)*128 + t0],
             s8[q*4]*coef_f(t0), s8[q*4+1]*coef_f(t0+1),
             s8[q*4+2]*coef_f(t0+2), s8[q*4+3]*coef_f(t0+3));
    }
  }
}

// ================= K3: h1 (48) + err (48) -> grid 96 =================
__global__ __launch_bounds__(256, 2)
void k3_h1err(Prm p)
{
  __shared__ float red[4][64][36];
  int t = blockIdx.x;
  if (t < 48) {
    gemm_task<3,0,true,true,true,false,false>(p.yb, p.cprojT, p.c_proj_b, p.x, 1.f,
        p.h1, nullptr, nullptr, 256, 384, t % 6, t / 6, red);
  } else {
    int tt2 = t - 48;
    gemm_task<6,0,false,true,false,true,true>(p.ab, p.w2tr, nullptr, p.vmb, -1.f,
        nullptr, p.errB, p.errT, 256, 384, tt2 % 6, tt2 / 6, red);
  }
}

// ================= K4: LN2 (64) + dh (96) -> grid 160 =================
__global__ __launch_bounds__(256, 2)
void k4_ln2dh(Prm p)
{
  __shared__ float red[4][64][36];
  int t = blockIdx.x;
  const int tid = threadIdx.x, w = tid >> 6, lane = tid & 63;
  if (t < 64) {
    int row = t*4 + w;
    const float* src = p.h1 + (long)row*384;
    float v[6];
    #pragma unroll
    for (int i = 0; i < 6; ++i) v[i] = src[lane + i*64];
    float mu = wave_sum(v[0]+v[1]+v[2]+v[3]+v[4]+v[5]) * (1.f/384.f);
    float sq = 0.f;
    #pragma unroll
    for (int i = 0; i < 6; ++i) { float d = v[i]-mu; sq += d*d; }
    float rstd = rsqrtf(wave_sum(sq)*(1.f/384.f) + 1e-5f);
    u16* dst = p.h2n + (long)row*384;
    #pragma unroll
    for (int i = 0; i < 6; ++i) {
      int cc = lane + i*64;
      dst[cc] = f2bf((v[i]-mu)*rstd*p.ln2_g[cc] + p.ln2_b[cc]);
    }
  } else {
    int tt2 = t - 64;
    int xx = tt2 % 12, yy = tt2 / 12;
    int mBase = yy*32, nBase = xx*64;
    mfma_core<3>(p.errB, p.w2pl, 256, mBase, nBase, red);
    float v[8]; int row0, col;
    reduce8(red, v, row0, col);
    int c = nBase + col;
    #pragma unroll
    for (int q = 0; q < 8; ++q) {
      int r = mBase + row0 + q;
      float h = p.hhb[(long)r*768 + c];
      float sg = 1.f/(1.f + expf(-h));
      v[q] = v[q] * (sg*(1.f + h*(1.f - sg)));
    }
    #pragma unroll
    for (int q = 0; q < 2; ++q) {
      int r = mBase + row0 + q*4;
      int zz = r >> 7, t0 = r & 127;
      st_tr4(&p.dhT[((long)zz*768 + c)*128 + t0], v[q*4], v[q*4+1], v[q*4+2], v[q*4+3]);
    }
  }
}

// ================= K5: fco (192) + wupd1 (288) + wupd2 (288) -> grid 768 =================
__global__ __launch_bounds__(256, 2)
void k5_fcowupd(Prm p)
{
  __shared__ float red[4][64][36];
  int t = blockIdx.x;
  if (t < 192) {
    gemm_task<3,1,true,false,false,true,false>(p.h2n, p.fcT, p.fc_b, nullptr, 0.f,
        nullptr, p.fco, nullptr, 256, 1536, t % 24, t / 24, red);
  } else {
    const u16 *A, *BT; const float* W0; u16* Oz; int M, N, xx, yy, z;
    if (t < 480) {
      int tt2 = t - 192;
      xx = tt2 % 12; yy = (tt2 / 12) % 12; z = tt2 / 144;
      M = 384; N = 768;
      A = p.kmTc + (long)z*M*128; BT = p.dhT + (long)z*N*128;
      W0 = p.mem_w1; Oz = p.w1fT + (long)z*M*N;
    } else {
      int tt2 = t - 480;
      xx = tt2 % 6; yy = (tt2 / 6) % 24; z = tt2 / 144;
      M = 768; N = 384;
      A = p.abTc + (long)z*M*128; BT = p.errT + (long)z*N*128;
      W0 = p.mem_w2; Oz = p.w2fT + (long)z*M*N;
    }
    int mBase = yy*32, nBase = xx*64;
    mfma_core<1>(A, BT, M, mBase, nBase, red);
    float v[8]; int row0, col;
    reduce8(red, v, row0, col);
    int c = nBase + col;
    #pragma unroll
    for (int q = 0; q < 8; ++q) {
      int r = mBase + row0 + q;
      v[q] = p.dpow*W0[(long)r*N + c] + p.scale*v[q];
    }
    int r0 = mBase + row0;
    st_tr4(&Oz[(long)c*M + r0],     v[0], v[1], v[2], v[3]);
    st_tr4(&Oz[(long)c*M + r0 + 4], v[4], v[5], v[6], v[7]);
  }
}

// ================= K6: h2 (grid 48) =================
__global__ __launch_bounds__(256, 2)
void k6_h2(Prm p)
{
  __shared__ float red[4][64][36];
  int t = blockIdx.x;
  gemm_task<12,0,true,true,true,true,false>(p.fco, p.prT, p.pr_b, p.h1, 1.f,
      p.h2, p.h2b, nullptr, 256, 384, t % 6, t / 6, red);
}

// ================= K7: ub = silu(h2 @ w1f) (grid 96) =================
__global__ __launch_bounds__(256, 2)
void k7_ub(Prm p)
{
  __shared__ float red[4][64][36];
  int t = blockIdx.x;
  int z = t / 48, rr = t % 48;
  gemm_task<3,2,false,false,false,true,false>(
      p.h2b + (long)z*128*384, p.w1fT + (long)z*768*384, nullptr, nullptr, 0.f,
      nullptr, p.ub + (long)z*128*768, nullptr, 128, 768, rr % 12, rr / 12, red);
}

// ================= K8: out = h2 + ub @ w2f (grid 48) =================
__global__ __launch_bounds__(256, 2)
void k8_out(Prm p)
{
  __shared__ float red[4][64][36];
  int t = blockIdx.x;
  int z = t / 24, rr = t % 24;
  gemm_task<6,0,false,true,true,false,false>(
      p.ub + (long)z*128*768, p.w2fT + (long)z*384*768, nullptr,
      p.h2 + (long)z*128*384, 1.f,
      p.outp + (long)z*128*384, nullptr, nullptr, 128, 384, rr % 6, rr / 6, red);
}

// ---------- launch ----------
extern "C" void kernel_launch(void* const* d_in, const int* in_sizes, int n_in,
                              void* d_out, int out_size, void* d_ws, size_t ws_size,
                              hipStream_t stream)
{
  Prm p;
  p.x        = (const float*)d_in[0];
  p.c_attn_w = (const float*)d_in[1];
  p.c_attn_b = (const float*)d_in[2];
  p.c_proj_w = (const float*)d_in[3];
  p.c_proj_b = (const float*)d_in[4];
  p.ln1_g    = (const float*)d_in[5];
  p.ln1_b    = (const float*)d_in[6];
  p.ln2_g    = (const float*)d_in[7];
  p.ln2_b    = (const float*)d_in[8];
  p.fc_w     = (const float*)d_in[9];
  p.fc_b     = (const float*)d_in[10];
  p.pr_w     = (const float*)d_in[11];
  p.pr_b     = (const float*)d_in[12];
  p.mem_w1   = (const float*)d_in[13];
  p.mem_w2   = (const float*)d_in[14];
  p.wk       = (const float*)d_in[15];
  p.wv       = (const float*)d_in[16];
  p.mem_q    = (const float*)d_in[17];
  p.persist  = (const float*)d_in[18];

  float* f = (float*)d_ws;
  p.qkv = f;            f += 296L*1152;
  p.vmb = f;            f += 256L*384;
  p.h1  = f;            f += 256L*384;
  p.h2  = f;            f += 256L*384;
  p.hhb = f;            f += 256L*768;
  u16* b = (u16*)f;
  p.cattnT = b;  b += 1152L*384;
  p.cprojT = b;  b += 384L*384;
  p.wkT    = b;  b += 384L*384;
  p.wvT    = b;  b += 384L*384;
  p.fcT    = b;  b += 1536L*384;
  p.prT    = b;  b += 384L*1536;
  p.w1tr   = b;  b += 768L*384;
  p.w2tr   = b;  b += 384L*768;
  p.w2pl   = b;  b += 768L*384;
  p.memq   = b;  b += 16L*384;
  p.seqb   = b;  b += 2L*TT*384;
  p.yb     = b;  b += 256L*384;
  p.h2n    = b;  b += 256L*384;
  p.fco    = b;  b += 256L*1536;
  p.h2b    = b;  b += 256L*384;
  p.kmb    = b;  b += 256L*384;
  p.kmTc   = b;  b += 2L*384*128;
  p.ab     = b;  b += 256L*768;
  p.abTc   = b;  b += 2L*768*128;
  p.errB   = b;  b += 256L*384;
  p.errT   = b;  b += 2L*384*128;
  p.dhT    = b;  b += 2L*768*128;
  p.w1fT   = b;  b += 2L*768*384;
  p.w2fT   = b;  b += 2L*384*768;
  p.ub     = b;  b += 2L*128*768;
  p.outp   = (float*)d_out;
  p.dpow   = powf(0.999f, 128.f);
  p.scale  = -0.001f;

  hipLaunchKernelGGL(k0_prep,    dim3(2952), dim3(256), 0, stream, p);
  hipLaunchKernelGGL(k0c_retr,   dim3(6),    dim3(256), 0, stream, p);
  hipLaunchKernelGGL(k1_qkv,     dim3(300),  dim3(256), 0, stream, p);
  hipLaunchKernelGGL(k2_attn_hh, dim3(480),  dim3(256), 0, stream, p);
  hipLaunchKernelGGL(k3_h1err,   dim3(96),   dim3(256), 0, stream, p);
  hipLaunchKernelGGL(k4_ln2dh,   dim3(160),  dim3(256), 0, stream, p);
  hipLaunchKernelGGL(k5_fcowupd, dim3(768),  dim3(256), 0, stream, p);
  hipLaunchKernelGGL(k6_h2,      dim3(48),   dim3(256), 0, stream, p);
  hipLaunchKernelGGL(k7_ub,      dim3(96),   dim3(256), 0, stream, p);
  hipLaunchKernelGGL(k8_out,     dim3(48),   dim3(256), 0, stream, p);
}

// Round 10
// 92.620 us; speedup vs baseline: 1.3332x; 1.3332x over previous
//
#include <hip/hip_runtime.h>
#include <math.h>

#define B_ 2
#define T_ 128
#define Cc 384
#define NH_ 6
#define HD 64
#define Hh 768
#define P_ 4
#define M_ 16
#define PL_ 20
#define TT 148

typedef unsigned short u16;
typedef short short8 __attribute__((ext_vector_type(8)));
typedef float f32x4 __attribute__((ext_vector_type(4)));

// ---------- helpers ----------
__device__ __forceinline__ u16 f2bf(float f) {
  unsigned int u = __float_as_uint(f);
  u += 0x7FFFu + ((u >> 16) & 1u);
  return (u16)(u >> 16);
}
__device__ __forceinline__ float siluf(float v) { return v / (1.f + expf(-v)); }
__device__ __forceinline__ float geluf(float v) {
  float x3 = v*v*v;
  return 0.5f*v*(1.f + tanhf(0.7978845608028654f*(v + 0.044715f*x3)));
}
template<int ACT> __device__ __forceinline__ float act_apply(float v) {
  if (ACT == 1) return geluf(v);
  if (ACT == 2) return siluf(v);
  return v;
}
__device__ __forceinline__ float coef_f(int k) {
  float e = (float)(T_ - k);
  return (exp2f(e * -0.00144342f) - exp2f(e * -0.15200310f)) * (1.0f/0.099f);
}
__device__ __forceinline__ void st_tr4(u16* dst, float v0, float v1, float v2, float v3) {
  union { u16 u[4]; uint2 d; } q;
  q.u[0]=f2bf(v0); q.u[1]=f2bf(v1); q.u[2]=f2bf(v2); q.u[3]=f2bf(v3);
  *(uint2*)dst = q.d;
}
__device__ __forceinline__ float wave_sum(float s) {
  #pragma unroll
  for (int off = 32; off; off >>= 1) s += __shfl_xor(s, off);
  return s;
}

// ---------- params ----------
struct Prm {
  const float *x,*c_attn_w,*c_attn_b,*c_proj_w,*c_proj_b,*ln1_g,*ln1_b,*ln2_g,*ln2_b,
              *fc_w,*fc_b,*pr_w,*pr_b,*mem_w1,*mem_w2,*wk,*wv,*mem_q,*persist;
  float *qkv,*vmb,*h1,*h2,*hhb,*outp;
  u16 *cattnT,*cprojT,*wkT,*wvT,*fcT,*prT,*w1tr,*w2tr,*w2pl,*memq,*hid,*seqb,*yb,*h2n,
      *fco,*h2b,*kmb,*kmTc,*ab,*abTc,*errB,*errT,*dhT,*w1fT,*w2fT,*ub;
  float scale, dpow;
};

// ---------- MFMA split-K core: 4 waves share a 32x64 tile over K/4 each ----------
template<int KSTEPS>   // per-wave K-steps; total K = KSTEPS*128
__device__ __forceinline__ void mfma_core(const u16* __restrict__ A,
    const u16* __restrict__ BT, int M, int mBase, int nBase, float (*red)[64][36])
{
  const long K = (long)KSTEPS * 128;
  int l = threadIdx.x & 63, w = threadIdx.x >> 6;
  int lr = l & 15, kg = l >> 4;
  long r0 = (long)min(mBase + lr, M - 1);
  long r1 = (long)min(mBase + 16 + lr, M - 1);
  long c0 = nBase + lr;
  long ko = (long)w * KSTEPS * 32 + kg * 8;
  const u16* pa0 = A + r0*K + ko;
  const u16* pa1 = A + r1*K + ko;
  const u16* pb0 = BT + c0*K + ko;
  const u16* pb1 = BT + (c0+16)*K + ko;
  const u16* pb2 = BT + (c0+32)*K + ko;
  const u16* pb3 = BT + (c0+48)*K + ko;
  f32x4 acc[2][4] = {};
  short8 a0 = *(const short8*)pa0, a1 = *(const short8*)pa1;
  short8 b0 = *(const short8*)pb0, b1 = *(const short8*)pb1;
  short8 b2 = *(const short8*)pb2, b3 = *(const short8*)pb3;
  #pragma unroll
  for (int t = 0; t < KSTEPS; ++t) {
    short8 xa0=a0, xa1=a1, xb0=b0, xb1=b1, xb2=b2, xb3=b3;
    if (t+1 < KSTEPS) {
      int o = (t+1)*32;
      a0 = *(const short8*)(pa0+o); a1 = *(const short8*)(pa1+o);
      b0 = *(const short8*)(pb0+o); b1 = *(const short8*)(pb1+o);
      b2 = *(const short8*)(pb2+o); b3 = *(const short8*)(pb3+o);
    }
    acc[0][0] = __builtin_amdgcn_mfma_f32_16x16x32_bf16(xa0, xb0, acc[0][0], 0,0,0);
    acc[0][1] = __builtin_amdgcn_mfma_f32_16x16x32_bf16(xa0, xb1, acc[0][1], 0,0,0);
    acc[0][2] = __builtin_amdgcn_mfma_f32_16x16x32_bf16(xa0, xb2, acc[0][2], 0,0,0);
    acc[0][3] = __builtin_amdgcn_mfma_f32_16x16x32_bf16(xa0, xb3, acc[0][3], 0,0,0);
    acc[1][0] = __builtin_amdgcn_mfma_f32_16x16x32_bf16(xa1, xb0, acc[1][0], 0,0,0);
    acc[1][1] = __builtin_amdgcn_mfma_f32_16x16x32_bf16(xa1, xb1, acc[1][1], 0,0,0);
    acc[1][2] = __builtin_amdgcn_mfma_f32_16x16x32_bf16(xa1, xb2, acc[1][2], 0,0,0);
    acc[1][3] = __builtin_amdgcn_mfma_f32_16x16x32_bf16(xa1, xb3, acc[1][3], 0,0,0);
  }
  #pragma unroll
  for (int i = 0; i < 2; ++i)
    #pragma unroll
    for (int j = 0; j < 4; ++j)
      *(f32x4*)&red[w][j*16 + lr][i*16 + kg*4] = acc[i][j];
  __syncthreads();
}

__device__ __forceinline__ void reduce8(float (*red)[64][36], float v[8], int& row0, int& col) {
  int tid = threadIdx.x;
  col = tid & 63;
  row0 = (tid >> 6) * 8;
  #pragma unroll
  for (int q = 0; q < 2; ++q) {
    f32x4 s = *(f32x4*)&red[0][col][row0 + q*4];
    s += *(f32x4*)&red[1][col][row0 + q*4];
    s += *(f32x4*)&red[2][col][row0 + q*4];
    s += *(f32x4*)&red[3][col][row0 + q*4];
    v[q*4+0] = s[0]; v[q*4+1] = s[1]; v[q*4+2] = s[2]; v[q*4+3] = s[3];
  }
}

template<int KSTEPS, int ACT, bool BIAS, bool RES, bool STF, bool STB, bool STTR>
__device__ __forceinline__ void gemm_task(const u16* A, const u16* BT,
    const float* bias, const float* res, float rscale,
    float* outF, u16* outB, u16* outT, int M, int N,
    int xx, int yy, float (*red)[64][36])
{
  int mBase = yy*32, nBase = xx*64;
  mfma_core<KSTEPS>(A, BT, M, mBase, nBase, red);
  float v[8]; int row0, col;
  reduce8(red, v, row0, col);
  int c = nBase + col;
  float bv = BIAS ? bias[c] : 0.f;
  #pragma unroll
  for (int q = 0; q < 8; ++q) {
    int r = mBase + row0 + q;
    float val = act_apply<ACT>(v[q] + bv);
    if (RES && r < M) val += rscale * res[(long)r*N + c];
    v[q] = val;
    if (r < M) {
      if (STF) outF[(long)r*N + c] = val;
      if (STB) outB[(long)r*N + c] = f2bf(val);
    }
  }
  if (STTR) {
    #pragma unroll
    for (int q = 0; q < 2; ++q) {
      int r = mBase + row0 + q*4;
      if (r < M) {
        int zz = r >> 7, t0 = r & 127;
        st_tr4(&outT[((long)zz*N + c)*128 + t0], v[q*4], v[q*4+1], v[q*4+2], v[q*4+3]);
      }
    }
  }
}

// ================= K0: transposes + plain converts + LN1 (grid 2952) =================
__global__ __launch_bounds__(256)
void k0_prep(Prm p)
{
  __shared__ float lds[1056];
  const int t = blockIdx.x;
  const int tid = threadIdx.x, w = tid >> 6, lane = tid & 63;
  if (t < 2592) {
    const float* src; u16* dst; int K, N, tile;
    int b = t;
    if (b < 432)       { src=p.c_attn_w; dst=p.cattnT; K=384;  N=1152; tile=b; }
    else if (b < 576)  { src=p.c_proj_w; dst=p.cprojT; K=384;  N=384;  tile=b-432; }
    else if (b < 720)  { src=p.wk;       dst=p.wkT;    K=384;  N=384;  tile=b-576; }
    else if (b < 864)  { src=p.wv;       dst=p.wvT;    K=384;  N=384;  tile=b-720; }
    else if (b < 1440) { src=p.fc_w;     dst=p.fcT;    K=384;  N=1536; tile=b-864; }
    else if (b < 2016) { src=p.pr_w;     dst=p.prT;    K=1536; N=384;  tile=b-1440; }
    else if (b < 2304) { src=p.mem_w1;   dst=p.w1tr;   K=384;  N=768;  tile=b-2016; }
    else               { src=p.mem_w2;   dst=p.w2tr;   K=768;  N=384;  tile=b-2304; }
    int ntx = N >> 5;
    int n0 = (tile % ntx) << 5, k0 = (tile / ntx) << 5;
    float (*fl)[33] = reinterpret_cast<float(*)[33]>(lds);
    int tr = tid >> 3, tc4 = (tid & 7) << 2;
    float4 vv = *(const float4*)&src[(long)(k0 + tr)*N + n0 + tc4];
    fl[tr][tc4] = vv.x; fl[tr][tc4+1] = vv.y; fl[tr][tc4+2] = vv.z; fl[tr][tc4+3] = vv.w;
    __syncthreads();
    st_tr4(&dst[(long)(n0 + tr)*K + k0 + tc4],
           fl[tc4][tr], fl[tc4+1][tr], fl[tc4+2][tr], fl[tc4+3][tr]);
  } else if (t < 2888) {
    int i = (t - 2592)*256 + tid;
    if (i < 73728) {
      float4 v = *(const float4*)&p.mem_w2[(long)i*4];
      st_tr4(&p.w2pl[(long)i*4], v.x, v.y, v.z, v.w);
    } else if (i < 73728 + 1536) {
      int j = i - 73728;
      float4 v = *(const float4*)&p.mem_q[(long)j*4];
      st_tr4(&p.memq[(long)j*4], v.x, v.y, v.z, v.w);
    } else if (i < 73728 + 1536 + 384) {
      int j = i - 73728 - 1536;
      float4 v = *(const float4*)&p.persist[(long)j*4];
      st_tr4(&p.seqb[(long)j*4], v.x, v.y, v.z, v.w);
      st_tr4(&p.seqb[(long)TT*384 + j*4], v.x, v.y, v.z, v.w);
    }
  } else {
    int row = (t - 2888)*4 + w;
    const float* src = p.x + (long)row*384;
    float v[6];
    #pragma unroll
    for (int i = 0; i < 6; ++i) v[i] = src[lane + i*64];
    float mu = wave_sum(v[0]+v[1]+v[2]+v[3]+v[4]+v[5]) * (1.f/384.f);
    float sq = 0.f;
    #pragma unroll
    for (int i = 0; i < 6; ++i) { float d = v[i]-mu; sq += d*d; }
    float rstd = rsqrtf(wave_sum(sq)*(1.f/384.f) + 1e-5f);
    u16* dst = p.seqb + ((long)(row >> 7)*TT + PL_ + (row & 127))*384;
    #pragma unroll
    for (int i = 0; i < 6; ++i) {
      int cc = lane + i*64;
      dst[cc] = f2bf((v[i]-mu)*rstd*p.ln1_g[cc] + p.ln1_b[cc]);
    }
  }
}

// ================= K0b: hid = silu(memq @ w1tr)  (grid 12) =================
__global__ __launch_bounds__(256, 2)
void k0b_hid(Prm p)
{
  __shared__ float red[4][64][36];
  gemm_task<3,2,false,false,false,true,false>(p.memq, p.w1tr, nullptr, nullptr, 0.f,
      nullptr, p.hid, nullptr, 16, 768, blockIdx.x, 0, red);
}

// ================= K0c: retr = hid @ w2tr -> seq rows 4..19 both batches (grid 6) =================
__global__ __launch_bounds__(256, 2)
void k0c_retr(Prm p)
{
  __shared__ float red[4][64][36];
  int nBase = blockIdx.x*64;
  mfma_core<6>(p.hid, p.w2tr, 16, 0, nBase, red);
  float v[8]; int row0, col;
  reduce8(red, v, row0, col);
  int c = nBase + col;
  #pragma unroll
  for (int q = 0; q < 8; ++q) {
    int r = row0 + q;
    if (r < 16) {
      u16 bv = f2bf(v[q]);
      p.seqb[(long)(P_ + r)*384 + c] = bv;
      p.seqb[(long)(TT + P_ + r)*384 + c] = bv;
    }
  }
}

// ================= K1: fused qkv / km / vm (grid 300) =================
__global__ __launch_bounds__(256, 2)
void k1_qkv(Prm p)
{
  __shared__ float red[4][64][36];
  int t = blockIdx.x;
  int xx = t % 30, yy = t / 30;
  int nb = xx * 64;
  const u16* BT; int n0, seg;
  if (nb < 1152)      { BT = p.cattnT; n0 = nb;        seg = 0; }
  else if (nb < 1536) { BT = p.wkT;    n0 = nb - 1152; seg = 1; }
  else                { BT = p.wvT;    n0 = nb - 1536; seg = 2; }
  int mBase = yy*32;
  mfma_core<3>(p.seqb, BT, 296, mBase, n0, red);
  float v[8]; int row0, col;
  reduce8(red, v, row0, col);
  int c = n0 + col;
  if (seg == 0) {
    float bv = p.c_attn_b[c];
    #pragma unroll
    for (int q = 0; q < 8; ++q) {
      int r = mBase + row0 + q;
      if (r < 296) p.qkv[(long)r*1152 + c] = v[q] + bv;
    }
  } else if (seg == 1) {
    #pragma unroll
    for (int q = 0; q < 8; ++q) {
      int r = mBase + row0 + q;
      if (r < 296) {
        int z = r/148, tt2 = r - 20 - z*148;
        if (tt2 >= 0) p.kmb[((long)z*128 + tt2)*384 + c] = f2bf(v[q]);
      }
    }
    #pragma unroll
    for (int q = 0; q < 2; ++q) {
      int r = mBase + row0 + q*4;
      if (r < 296) {
        int z = r/148, t0 = r - 20 - z*148;
        if (t0 >= 0)
          st_tr4(&p.kmTc[((long)z*384 + c)*128 + t0],
                 v[q*4]*coef_f(t0), v[q*4+1]*coef_f(t0+1),
                 v[q*4+2]*coef_f(t0+2), v[q*4+3]*coef_f(t0+3));
      }
    }
  } else {
    #pragma unroll
    for (int q = 0; q < 8; ++q) {
      int r = mBase + row0 + q;
      if (r < 296) {
        int z = r/148, tt2 = r - 20 - z*148;
        if (tt2 >= 0) p.vmb[((long)z*128 + tt2)*384 + c] = v[q];
      }
    }
  }
}

// ================= K2: attention (384) + hh/ab/abTc (96) -> grid 480 =================
__global__ __launch_bounds__(256, 2)
void k2_attn_hh(Prm p)
{
  __shared__ float red[4][64][36];
  const int t = blockIdx.x;
  const int tid = threadIdx.x, w = tid >> 6, lane = tid & 63;
  if (t < 384) {
    float* ldsf = (float*)red;
    float* qs = ldsf + w*64;
    float* pp = ldsf + 256 + w*152;
    int tt = t*4 + w;
    int qr = PL_ + (tt & 127);
    int h  = (tt >> 7) % 6;
    int b  = (tt / 768) & 1;
    const float* base = p.qkv + (long)b*TT*1152;
    qs[lane] = base[(long)qr*1152 + h*64 + lane];
    float mloc = -1e30f;
    for (int k = lane; k < TT; k += 64) {
      float s = -1e30f;
      if (k <= qr) {
        const float* kp = base + (long)k*1152 + 384 + h*64;
        float acc = 0.f;
        #pragma unroll
        for (int d = 0; d < 64; ++d) acc += qs[d]*kp[d];
        s = acc * 0.125f;
      }
      pp[k] = s;
      mloc = fmaxf(mloc, s);
    }
    #pragma unroll
    for (int off = 32; off; off >>= 1) mloc = fmaxf(mloc, __shfl_xor(mloc, off));
    float ssum = 0.f;
    for (int k = lane; k < TT; k += 64) {
      float e = (k <= qr) ? expf(pp[k] - mloc) : 0.f;
      pp[k] = e; ssum += e;
    }
    ssum = wave_sum(ssum);
    float inv = 1.f / ssum;
    float acc = 0.f;
    const float* vb = base + 768 + h*64 + lane;
    int k = 0;
    for (; k + 4 <= qr + 1; k += 4)
      acc += pp[k]*vb[(long)k*1152] + pp[k+1]*vb[(long)(k+1)*1152]
           + pp[k+2]*vb[(long)(k+2)*1152] + pp[k+3]*vb[(long)(k+3)*1152];
    for (; k <= qr; ++k) acc += pp[k]*vb[(long)k*1152];
    p.yb[((long)b*128 + (tt & 127))*384 + h*64 + lane] = f2bf(acc * inv);
  } else {
    int tt2 = t - 384;
    int xx = tt2 % 12, yy = tt2 / 12;
    int mBase = yy*32, nBase = xx*64;
    mfma_core<3>(p.kmb, p.w1tr, 256, mBase, nBase, red);
    float v[8]; int row0, col;
    reduce8(red, v, row0, col);
    int c = nBase + col;
    float s8[8];
    #pragma unroll
    for (int q = 0; q < 8; ++q) {
      int r = mBase + row0 + q;
      p.hhb[(long)r*768 + c] = v[q];
      s8[q] = siluf(v[q]);
      p.ab[(long)r*768 + c] = f2bf(s8[q]);
    }
    #pragma unroll
    for (int q = 0; q < 2; ++q) {
      int r = mBase + row0 + q*4;
      int zz = r >> 7, t0 = r & 127;
      st_tr4(&p.abTc[((long)zz*768 + c)*128 + t0],
             s8[q*4]*coef_f(t0), s8[q*4+1]*coef_f(t0+1),
             s8[q*4+2]*coef_f(t0+2), s8[q*4+3]*coef_f(t0+3));
    }
  }
}

// ================= K3: h1 (48) + err (48) -> grid 96 =================
__global__ __launch_bounds__(256, 2)
void k3_h1err(Prm p)
{
  __shared__ float red[4][64][36];
  int t = blockIdx.x;
  if (t < 48) {
    gemm_task<3,0,true,true,true,false,false>(p.yb, p.cprojT, p.c_proj_b, p.x, 1.f,
        p.h1, nullptr, nullptr, 256, 384, t % 6, t / 6, red);
  } else {
    int tt2 = t - 48;
    gemm_task<6,0,false,true,false,true,true>(p.ab, p.w2tr, nullptr, p.vmb, -1.f,
        nullptr, p.errB, p.errT, 256, 384, tt2 % 6, tt2 / 6, red);
  }
}

// ================= K4: LN2 (64) + dh (96) -> grid 160 =================
__global__ __launch_bounds__(256, 2)
void k4_ln2dh(Prm p)
{
  __shared__ float red[4][64][36];
  int t = blockIdx.x;
  const int tid = threadIdx.x, w = tid >> 6, lane = tid & 63;
  if (t < 64) {
    int row = t*4 + w;
    const float* src = p.h1 + (long)row*384;
    float v[6];
    #pragma unroll
    for (int i = 0; i < 6; ++i) v[i] = src[lane + i*64];
    float mu = wave_sum(v[0]+v[1]+v[2]+v[3]+v[4]+v[5]) * (1.f/384.f);
    float sq = 0.f;
    #pragma unroll
    for (int i = 0; i < 6; ++i) { float d = v[i]-mu; sq += d*d; }
    float rstd = rsqrtf(wave_sum(sq)*(1.f/384.f) + 1e-5f);
    u16* dst = p.h2n + (long)row*384;
    #pragma unroll
    for (int i = 0; i < 6; ++i) {
      int cc = lane + i*64;
      dst[cc] = f2bf((v[i]-mu)*rstd*p.ln2_g[cc] + p.ln2_b[cc]);
    }
  } else {
    int tt2 = t - 64;
    int xx = tt2 % 12, yy = tt2 / 12;
    int mBase = yy*32, nBase = xx*64;
    mfma_core<3>(p.errB, p.w2pl, 256, mBase, nBase, red);
    float v[8]; int row0, col;
    reduce8(red, v, row0, col);
    int c = nBase + col;
    #pragma unroll
    for (int q = 0; q < 8; ++q) {
      int r = mBase + row0 + q;
      float h = p.hhb[(long)r*768 + c];
      float sg = 1.f/(1.f + expf(-h));
      v[q] = v[q] * (sg*(1.f + h*(1.f - sg)));
    }
    #pragma unroll
    for (int q = 0; q < 2; ++q) {
      int r = mBase + row0 + q*4;
      int zz = r >> 7, t0 = r & 127;
      st_tr4(&p.dhT[((long)zz*768 + c)*128 + t0], v[q*4], v[q*4+1], v[q*4+2], v[q*4+3]);
    }
  }
}

// ================= K5: fco (192) + wupd1 (288) + wupd2 (288) -> grid 768 =================
__global__ __launch_bounds__(256, 2)
void k5_fcowupd(Prm p)
{
  __shared__ float red[4][64][36];
  int t = blockIdx.x;
  if (t < 192) {
    gemm_task<3,1,true,false,false,true,false>(p.h2n, p.fcT, p.fc_b, nullptr, 0.f,
        nullptr, p.fco, nullptr, 256, 1536, t % 24, t / 24, red);
  } else {
    const u16 *A, *BT; const float* W0; u16* Oz; int M, N, xx, yy, z;
    if (t < 480) {
      int tt2 = t - 192;
      xx = tt2 % 12; yy = (tt2 / 12) % 12; z = tt2 / 144;
      M = 384; N = 768;
      A = p.kmTc + (long)z*M*128; BT = p.dhT + (long)z*N*128;
      W0 = p.mem_w1; Oz = p.w1fT + (long)z*M*N;
    } else {
      int tt2 = t - 480;
      xx = tt2 % 6; yy = (tt2 / 6) % 24; z = tt2 / 144;
      M = 768; N = 384;
      A = p.abTc + (long)z*M*128; BT = p.errT + (long)z*N*128;
      W0 = p.mem_w2; Oz = p.w2fT + (long)z*M*N;
    }
    int mBase = yy*32, nBase = xx*64;
    mfma_core<1>(A, BT, M, mBase, nBase, red);
    float v[8]; int row0, col;
    reduce8(red, v, row0, col);
    int c = nBase + col;
    #pragma unroll
    for (int q = 0; q < 8; ++q) {
      int r = mBase + row0 + q;
      v[q] = p.dpow*W0[(long)r*N + c] + p.scale*v[q];
    }
    int r0 = mBase + row0;
    st_tr4(&Oz[(long)c*M + r0],     v[0], v[1], v[2], v[3]);
    st_tr4(&Oz[(long)c*M + r0 + 4], v[4], v[5], v[6], v[7]);
  }
}

// ================= K6: h2 (grid 48) =================
__global__ __launch_bounds__(256, 2)
void k6_h2(Prm p)
{
  __shared__ float red[4][64][36];
  int t = blockIdx.x;
  gemm_task<12,0,true,true,true,true,false>(p.fco, p.prT, p.pr_b, p.h1, 1.f,
      p.h2, p.h2b, nullptr, 256, 384, t % 6, t / 6, red);
}

// ================= K7: ub = silu(h2 @ w1f) (grid 96) =================
__global__ __launch_bounds__(256, 2)
void k7_ub(Prm p)
{
  __shared__ float red[4][64][36];
  int t = blockIdx.x;
  int z = t / 48, rr = t % 48;
  gemm_task<3,2,false,false,false,true,false>(
      p.h2b + (long)z*128*384, p.w1fT + (long)z*768*384, nullptr, nullptr, 0.f,
      nullptr, p.ub + (long)z*128*768, nullptr, 128, 768, rr % 12, rr / 12, red);
}

// ================= K8: out = h2 + ub @ w2f (grid 48) =================
__global__ __launch_bounds__(256, 2)
void k8_out(Prm p)
{
  __shared__ float red[4][64][36];
  int t = blockIdx.x;
  int z = t / 24, rr = t % 24;
  gemm_task<6,0,false,true,true,false,false>(
      p.ub + (long)z*128*768, p.w2fT + (long)z*384*768, nullptr,
      p.h2 + (long)z*128*384, 1.f,
      p.outp + (long)z*128*384, nullptr, nullptr, 128, 384, rr % 6, rr / 6, red);
}

// ---------- launch ----------
extern "C" void kernel_launch(void* const* d_in, const int* in_sizes, int n_in,
                              void* d_out, int out_size, void* d_ws, size_t ws_size,
                              hipStream_t stream)
{
  Prm p;
  p.x        = (const float*)d_in[0];
  p.c_attn_w = (const float*)d_in[1];
  p.c_attn_b = (const float*)d_in[2];
  p.c_proj_w = (const float*)d_in[3];
  p.c_proj_b = (const float*)d_in[4];
  p.ln1_g    = (const float*)d_in[5];
  p.ln1_b    = (const float*)d_in[6];
  p.ln2_g    = (const float*)d_in[7];
  p.ln2_b    = (const float*)d_in[8];
  p.fc_w     = (const float*)d_in[9];
  p.fc_b     = (const float*)d_in[10];
  p.pr_w     = (const float*)d_in[11];
  p.pr_b     = (const float*)d_in[12];
  p.mem_w1   = (const float*)d_in[13];
  p.mem_w2   = (const float*)d_in[14];
  p.wk       = (const float*)d_in[15];
  p.wv       = (const float*)d_in[16];
  p.mem_q    = (const float*)d_in[17];
  p.persist  = (const float*)d_in[18];

  float* f = (float*)d_ws;
  p.qkv = f;            f += 296L*1152;
  p.vmb = f;            f += 256L*384;
  p.h1  = f;            f += 256L*384;
  p.h2  = f;            f += 256L*384;
  p.hhb = f;            f += 256L*768;
  u16* b = (u16*)f;
  p.cattnT = b;  b += 1152L*384;
  p.cprojT = b;  b += 384L*384;
  p.wkT    = b;  b += 384L*384;
  p.wvT    = b;  b += 384L*384;
  p.fcT    = b;  b += 1536L*384;
  p.prT    = b;  b += 384L*1536;
  p.w1tr   = b;  b += 768L*384;
  p.w2tr   = b;  b += 384L*768;
  p.w2pl   = b;  b += 768L*384;
  p.memq   = b;  b += 16L*384;
  p.hid    = b;  b += 16L*768;
  p.seqb   = b;  b += 2L*TT*384;
  p.yb     = b;  b += 256L*384;
  p.h2n    = b;  b += 256L*384;
  p.fco    = b;  b += 256L*1536;
  p.h2b    = b;  b += 256L*384;
  p.kmb    = b;  b += 256L*384;
  p.kmTc   = b;  b += 2L*384*128;
  p.ab     = b;  b += 256L*768;
  p.abTc   = b;  b += 2L*768*128;
  p.errB   = b;  b += 256L*384;
  p.errT   = b;  b += 2L*384*128;
  p.dhT    = b;  b += 2L*768*128;
  p.w1fT   = b;  b += 2L*768*384;
  p.w2fT   = b;  b += 2L*384*768;
  p.ub     = b;  b += 2L*128*768;
  p.outp   = (float*)d_out;
  p.dpow   = powf(0.999f, 128.f);
  p.scale  = -0.001f;

  hipLaunchKernelGGL(k0_prep,    dim3(2952), dim3(256), 0, stream, p);
  hipLaunchKernelGGL(k0b_hid,    dim3(12),   dim3(256), 0, stream, p);
  hipLaunchKernelGGL(k0c_retr,   dim3(6),    dim3(256), 0, stream, p);
  hipLaunchKernelGGL(k1_qkv,     dim3(300),  dim3(256), 0, stream, p);
  hipLaunchKernelGGL(k2_attn_hh, dim3(480),  dim3(256), 0, stream, p);
  hipLaunchKernelGGL(k3_h1err,   dim3(96),   dim3(256), 0, stream, p);
  hipLaunchKernelGGL(k4_ln2dh,   dim3(160),  dim3(256), 0, stream, p);
  hipLaunchKernelGGL(k5_fcowupd, dim3(768),  dim3(256), 0, stream, p);
  hipLaunchKernelGGL(k6_h2,      dim3(48),   dim3(256), 0, stream, p);
  hipLaunchKernelGGL(k7_ub,      dim3(96),   dim3(256), 0, stream, p);
  hipLaunchKernelGGL(k8_out,     dim3(48),   dim3(256), 0, stream, p);
}